// Round 1
// baseline (57653.400 us; speedup 1.0000x reference)
//
#include <hip/hip_runtime.h>
#include <hip/hip_cooperative_groups.h>

namespace cg = cooperative_groups;

#define UNITS 3225
#define NBATCH 64
#define NSTEP 500
#define NH_SCALE 0.004472135954999579f   // 0.01*sqrt(2*0.1)
#define NI_SCALE 0.004472135954999579f
#define WC_FLOATS 2699776
#define HSZ 103200000ll                  // 64*500*3225

// region tables: str, fsi, gpe, stn, snr, thal, alm
__constant__ int   c_dst[7]  = {0,512,665,1177,1689,2201,2713};
__constant__ int   c_rows[7] = {512,153,512,512,512,512,512};
__constant__ int   c_wid[7]  = {1536,1024,256,512,768,871,1024};
__constant__ int   c_base[7] = {0,786432,943104,1074176,1336320,1729536,2175488};
__constant__ int   c_r0s[7]  = {0,512,256,665,0,1689,2201};
__constant__ int   c_r0l[7]  = {665,153,256,512,256,512,1024};
__constant__ int   c_r1s[7]  = {2201,2201,0,0,1177,2713,0};
__constant__ float c_ton[7]  = {0.1f,0.1f,0.6f,0.3f,0.6f,0.1f,0.1f};
__constant__ int   c_cs[8]   = {0,64,84,148,212,276,340,404};
__constant__ int   c_cbase[8]= {0,786432,943104,1074176,1336320,1729536,2175488,2699776};

__device__ __forceinline__ float ht_clip(float w) {
    return fminf(fmaxf(w, 1e-10f), 1.0f);
}

__global__ void build_w(
    const float* __restrict__ str2str, const float* __restrict__ thal2alm,
    const float* __restrict__ thal2str, const float* __restrict__ alm2alm,
    const float* __restrict__ alm2str, const float* __restrict__ alm2thal,
    const float* __restrict__ str2snr, const float* __restrict__ str2gpe,
    const float* __restrict__ gpe2stn, const float* __restrict__ stn2snr,
    const float* __restrict__ snr2thal, const float* __restrict__ fsi2str,
    const float* __restrict__ thal2fsi, const float* __restrict__ alm2fsi,
    const float* __restrict__ fsi2fsi, const int* __restrict__ smask,
    float* __restrict__ Wc)
{
    int tid = blockIdx.x * blockDim.x + threadIdx.x;
    if (tid >= WC_FLOATS) return;
    int r = 0;
    while (tid >= c_cbase[r+1]) ++r;
    int local = tid - c_cbase[r];
    int width = c_wid[r];
    int row = local / width;
    int c = local - row * width;
    int r0l = c_r0l[r];
    int v = (c < r0l) ? (c_r0s[r] + c) : (c_r1s[r] + (c - r0l));
    int i = row;
    int rv, j;
    if (v < 512)       { rv = 0; j = v; }
    else if (v < 665)  { rv = 1; j = v - 512; }
    else if (v < 1177) { rv = 2; j = v - 665; }
    else if (v < 1689) { rv = 3; j = v - 1177; }
    else if (v < 2201) { rv = 4; j = v - 1689; }
    else if (v < 2713) { rv = 5; j = v - 2201; }
    else               { rv = 6; j = v - 2713; }
    float val = 0.0f;
    switch (r) {
    case 0: // str rows: src str | fsi | thal(D1 rows) | alm(exc cols)
        if (rv == 0)      val = smask[i*512+j] ? -ht_clip(str2str[i*512+j]) : 0.0f;
        else if (rv == 1) val = -ht_clip(fsi2str[i*153+j]);
        else if (rv == 5) val = (i < 256) ? ht_clip(thal2str[i*512+j]) : 0.0f;
        else              val = (j < 359) ? ht_clip(alm2str[i*512+j]) : 0.0f;
        break;
    case 1: // fsi rows
        if (rv == 1)      val = -ht_clip(fsi2fsi[i*153+j]);
        else if (rv == 5) val = ht_clip(thal2fsi[i*512+j]);
        else              val = (j < 359) ? ht_clip(alm2fsi[i*512+j]) : 0.0f;
        break;
    case 2: // gpe rows: str D2 cols (j>=256)
        val = (j >= 256) ? -ht_clip(str2gpe[i*512+j]) : 0.0f;
        break;
    case 3: // stn rows: gpe
        val = -ht_clip(gpe2stn[i*512+j]);
        break;
    case 4: // snr rows: str D1 cols | stn
        if (rv == 0) val = (j < 256) ? -ht_clip(str2snr[i*512+j]) : 0.0f;
        else         val = ht_clip(stn2snr[i*512+j]);
        break;
    case 5: // thal rows: snr | alm exc
        if (rv == 4) val = -ht_clip(snr2thal[i*512+j]);
        else         val = (j < 359) ? ht_clip(alm2thal[i*512+j]) : 0.0f;
        break;
    default: // alm rows: thal | alm (signed)
        if (rv == 5) val = ht_clip(thal2alm[i*512+j]);
        else         val = (j < 359) ? ht_clip(alm2alm[i*512+j]) : -ht_clip(alm2alm[i*512+j]);
        break;
    }
    Wc[tid] = val;
}

struct Params {
    const float* inp;
    const float* cue;
    const float* inhib;
    const float* hn;
    const float* xn;
    const float* noise_hid;
    const float* noise_inp;
    const float* inp_w;
    const float* out_w;
    const float* Wc;
    float* hT0;
    float* hT1;
    float* out;
};

__global__ void __launch_bounds__(256) rnn_loop(Params p)
{
    cg::grid_group grid = cg::this_grid();
    const int tid  = threadIdx.x;
    const int lane = tid & 63;
    const int wv   = tid >> 6;
    const int bi   = blockIdx.x;

    int r = 0;
    while (bi >= c_cs[r+1]) ++r;
    const int lc    = bi - c_cs[r];
    const int row0  = lc * 8;
    const int nr    = min(8, c_rows[r] - row0);
    const int u0    = c_dst[r] + row0;
    const int width = c_wid[r];
    const float tonic = c_ton[r];
    const int r0s = c_r0s[r], r0l = c_r0l[r], r1s = c_r1s[r];
    const float* __restrict__ wr = p.Wc + c_base[r] + row0 * width;

    __shared__ float red[4][8][64];   // [wave][row][batch]
    __shared__ float htile[8*65];     // padded transpose tile

    const int r2 = tid >> 6;          // 0..3 (pointwise row group)
    const int b  = tid & 63;          // batch

    // x state lives in registers for the whole 500-step loop
    float xreg[2];
    #pragma unroll
    for (int pi = 0; pi < 2; ++pi) {
        int pr = r2 + 4*pi;
        xreg[pi] = 0.0f;
        if (pr < nr) {
            xreg[pi] = p.xn[b*UNITS + (u0+pr)];
            p.hT0[(u0+pr)*64 + b] = p.hn[b*UNITS + (u0+pr)];
        }
    }
    const bool outs_block = (bi >= 84 && bi < 148);  // gpe blocks (lightest) do readout
    grid.sync();

    const int c0 = (width * wv) >> 2;
    const int c1 = (width * (wv+1)) >> 2;
    const int a0 = c0, a1 = min(c1, r0l);
    const int b0 = max(c0, r0l), b1 = c1;

    for (int t = 0; t < NSTEP; ++t) {
        const float* __restrict__ rb = (t & 1) ? p.hT1 : p.hT0;
        float* __restrict__ wb = (t & 1) ? p.hT0 : p.hT1;

        // readout for previous step (h(t-1) lives in rb)
        if (outs_block && t > 0 && tid < 64) {
            int ob = bi - 84;
            float s = 0.0f;
            for (int jj = lane; jj < 359; jj += 64)
                s += rb[(2713+jj)*64 + ob] * p.out_w[jj];
            #pragma unroll
            for (int off = 32; off > 0; off >>= 1)
                s += __shfl_down(s, off, 64);
            if (lane == 0) p.out[HSZ + (long long)ob*NSTEP + (t-1)] = s;
        }

        // ---- matmul: 8 rows, this wave's quarter of the compact K range ----
        float acc[8];
        #pragma unroll
        for (int q = 0; q < 8; ++q) acc[q] = 0.0f;

        #pragma unroll 4
        for (int c = a0; c < a1; ++c) {
            float hv = rb[(r0s + c)*64 + lane];
            #pragma unroll
            for (int q = 0; q < 8; ++q) acc[q] += wr[q*width + c] * hv;
        }
        #pragma unroll 4
        for (int c = b0; c < b1; ++c) {
            float hv = rb[(r1s + (c - r0l))*64 + lane];
            #pragma unroll
            for (int q = 0; q < 8; ++q) acc[q] += wr[q*width + c] * hv;
        }

        #pragma unroll
        for (int q = 0; q < 8; ++q) red[wv][q][lane] = acc[q];
        __syncthreads();

        // ---- reduce + pointwise for this block's (8 rows x 64 batch) tile ----
        const float inp_eff = p.inp[b*NSTEP + t] + NI_SCALE * p.noise_inp[t*NBATCH + b];
        const float cue_b   = p.cue[b*NSTEP + t];
        #pragma unroll
        for (int pi = 0; pi < 2; ++pi) {
            int pr = r2 + 4*pi;
            if (pr < nr) {
                int u = u0 + pr;
                float mm = red[0][pr][b] + red[1][pr][b] + red[2][pr][b] + red[3][pr][b];
                float drive = mm + tonic;
                if (u < 665) drive += inp_eff * p.inp_w[u];
                if (u >= 2201 && u < 2713) drive += cue_b;
                drive += p.inhib[((long long)b*NSTEP + t)*UNITS + u];
                drive += NH_SCALE * p.noise_hid[((long long)t*NBATCH + b)*UNITS + u];
                float xv = xreg[pi];
                xv = xv + 0.1f*(drive - xv);
                xreg[pi] = xv;
                float h = fmaxf(xv, 0.0f);
                wb[u*64 + b] = h;            // coalesced [unit][batch] state write
                htile[pr*65 + b] = h;        // stage for transposed hs write
            }
        }
        __syncthreads();
        {
            // hs output: [b][t][u], 8 contiguous floats per batch row (32 B segments)
            int rr = tid & 7, bb = tid >> 3;   // bb 0..31, two passes
            if (rr < nr) {
                long long o = (long long)bb*(NSTEP*UNITS) + (long long)t*UNITS + (u0+rr);
                p.out[o] = htile[rr*65 + bb];
                p.out[o + 32ll*NSTEP*UNITS] = htile[rr*65 + bb + 32];
            }
        }
        grid.sync();
    }

    // readout for final step (h(499) lives in hT0 since 500 is even)
    if (outs_block && tid < 64) {
        int ob = bi - 84;
        const float* __restrict__ rb = p.hT0;
        float s = 0.0f;
        for (int jj = lane; jj < 359; jj += 64)
            s += rb[(2713+jj)*64 + ob] * p.out_w[jj];
        #pragma unroll
        for (int off = 32; off > 0; off >>= 1)
            s += __shfl_down(s, off, 64);
        if (lane == 0) p.out[HSZ + (long long)ob*NSTEP + (NSTEP-1)] = s;
    }
}

extern "C" void kernel_launch(void* const* d_in, const int* in_sizes, int n_in,
                              void* d_out, int out_size, void* d_ws, size_t ws_size,
                              hipStream_t stream)
{
    (void)in_sizes; (void)n_in; (void)out_size; (void)ws_size;
    const float* inp       = (const float*)d_in[0];
    const float* cue       = (const float*)d_in[1];
    const float* inhib     = (const float*)d_in[2];
    const float* hn        = (const float*)d_in[3];
    const float* xn        = (const float*)d_in[4];
    const float* noise_hid = (const float*)d_in[5];
    const float* noise_inp = (const float*)d_in[6];
    const float* str2str   = (const float*)d_in[7];
    const float* thal2alm  = (const float*)d_in[8];
    const float* thal2str  = (const float*)d_in[9];
    const float* alm2alm   = (const float*)d_in[10];
    const float* alm2str   = (const float*)d_in[11];
    const float* alm2thal  = (const float*)d_in[12];
    const float* str2snr   = (const float*)d_in[13];
    const float* str2gpe   = (const float*)d_in[14];
    const float* gpe2stn   = (const float*)d_in[15];
    const float* stn2snr   = (const float*)d_in[16];
    const float* snr2thal  = (const float*)d_in[17];
    const float* fsi2str   = (const float*)d_in[18];
    const float* thal2fsi  = (const float*)d_in[19];
    const float* alm2fsi   = (const float*)d_in[20];
    const float* fsi2fsi   = (const float*)d_in[21];
    const float* inp_w     = (const float*)d_in[22];
    const float* out_w     = (const float*)d_in[23];
    const int*   smask     = (const int*)d_in[24];

    float* Wc  = (float*)d_ws;                 // 2,699,776 floats (10.8 MB)
    float* hT0 = Wc + WC_FLOATS;               // [UNITS][64]
    float* hT1 = hT0 + UNITS*64;               // ping-pong buffer (~12.5 MB total)

    hipLaunchKernelGGL(build_w, dim3((WC_FLOATS+255)/256), dim3(256), 0, stream,
        str2str, thal2alm, thal2str, alm2alm, alm2str, alm2thal, str2snr, str2gpe,
        gpe2stn, stn2snr, snr2thal, fsi2str, thal2fsi, alm2fsi, fsi2fsi, smask, Wc);

    Params p;
    p.inp = inp; p.cue = cue; p.inhib = inhib; p.hn = hn; p.xn = xn;
    p.noise_hid = noise_hid; p.noise_inp = noise_inp;
    p.inp_w = inp_w; p.out_w = out_w; p.Wc = Wc;
    p.hT0 = hT0; p.hT1 = hT1; p.out = (float*)d_out;

    void* kargs[] = { &p };
    hipLaunchCooperativeKernel((void*)rnn_loop, dim3(404), dim3(256), kargs, 0, stream);
}